// Round 16
// baseline (188.018 us; speedup 1.0000x reference)
//
#include <hip/hip_runtime.h>

// SoftDTW: B=64, N=512, M=512, DIM=64, GAMMA=1.0, BANDWIDTH=0, BIG=1e10
constexpr int Bc   = 64;
constexpr int Nc   = 512;
constexpr int Mc   = 512;
constexpr int DIMc = 64;
constexpr float BIGc = 1e10f;
constexpr int CELLS = Nc * Mc;          // per-batch compact diag-major D (bf16, prescaled)
constexpr float LOG2E = 1.442695041f;
constexpr float LN2   = 0.6931471806f;
constexpr int ALARGE = 1 << 26;         // anchor for zero-states (E ~ 2^-ALARGE = 0)

struct TrueC  { static constexpr bool value = true;  };
struct FalseC { static constexpr bool value = false; };

typedef __attribute__((ext_vector_type(8))) short short8v;   // bf16x8 MFMA frag
typedef __attribute__((ext_vector_type(4))) float f32x4;     // MFMA accumulator

// compact diag storage: cell (row n, col m), g=n+m, lives at dOffm(g) + n
__device__ __forceinline__ int dOffm(int g) {
    if (g < 512) return g * (g + 1) / 2;
    int e = g - 512;
    return 131328 + e * 511 - e * (e - 1) / 2 - (g - 511);
}

// float -> bf16 bits, round-to-nearest-even
__device__ __forceinline__ unsigned short f2bf_rne(float f) {
    unsigned u = __builtin_bit_cast(unsigned, f);
    u += 0x7FFFu + ((u >> 16) & 1u);
    return (unsigned short)(u >> 16);
}
__device__ __forceinline__ float bf2f(unsigned short h) {
    return __builtin_bit_cast(float, (unsigned)h << 16);
}

// lane l <- lane l-1 across the 64-lane wave; lane 0 <- old
__device__ __forceinline__ float dpp_shr1_f(float v, float old) {
    return __builtin_bit_cast(float, __builtin_amdgcn_update_dpp(
        __builtin_bit_cast(int, old), __builtin_bit_cast(int, v), 0x138, 0xF, 0xF, false));
}
__device__ __forceinline__ int dpp_shr1_i(int v, int old) {
    return __builtin_amdgcn_update_dpp(old, v, 0x138, 0xF, 0xF, false);
}
__device__ __forceinline__ float f4c(const float4 v, int c) {
    switch (c & 3) { case 0: return v.x; case 1: return v.y;
                     case 2: return v.z; default: return v.w; }
}
__device__ __forceinline__ void f4set(float4& d, int c, float v) {
    switch (c & 3) { case 0: d.x = v; break; case 1: d.y = v; break;
                     case 2: d.z = v; break; default: d.w = v; }
}
__device__ __forceinline__ int i4c(const int4 v, int c) {
    switch (c & 3) { case 0: return v.x; case 1: return v.y;
                     case 2: return v.z; default: return v.w; }
}
__device__ __forceinline__ void i4set(int4& d, int c, int v) {
    switch (c & 3) { case 0: d.x = v; break; case 1: d.y = v; break;
                     case 2: d.z = v; break; default: d.w = v; }
}
// exponent-field add: F * 2^s for s in [-96, 0]; F normal positive
__device__ __forceinline__ float expadd(float F, int s) {
    return __builtin_bit_cast(float, __builtin_bit_cast(int, F) + (s << 23));
}

// ---------------- Kernel A (MFMA): D = (|x|^2+|y|^2-2*X.Y^T)*log2e -> diag bf16 --
__global__ __launch_bounds__(256)
void compute_D_mfma(const float* __restrict__ X, const float* __restrict__ Y,
                    unsigned short* __restrict__ Dc)
{
    __shared__ unsigned short Xs[128 * 72];
    __shared__ unsigned short Ys[128 * 72];
    __shared__ unsigned short Ct[128 * 132];
    __shared__ float xn2[128], ym2[128];

    const int b   = blockIdx.x;
    const int nt  = blockIdx.y >> 2;
    const int mt_ = blockIdx.y & 3;
    const int n0  = nt * 128, m0 = mt_ * 128;
    const int tid = threadIdx.x;

    const float* Xb = X + ((size_t)b * Nc + n0) * DIMc;
    const float* Yb = Y + ((size_t)b * Mc + m0) * DIMc;
    unsigned short* Db = Dc + (size_t)b * CELLS;

    {
        const float4* Xb4 = reinterpret_cast<const float4*>(Xb);
        const float4* Yb4 = reinterpret_cast<const float4*>(Yb);
        #pragma unroll
        for (int it = 0; it < 8; ++it) {
            const int c4 = tid + it * 256;
            const int row = c4 >> 4, k4 = (c4 & 15) * 4;
            float4 xv = Xb4[c4];
            float4 yv = Yb4[c4];
            ushort4 xs = make_ushort4(f2bf_rne(xv.x), f2bf_rne(xv.y),
                                      f2bf_rne(xv.z), f2bf_rne(xv.w));
            ushort4 ys = make_ushort4(f2bf_rne(yv.x), f2bf_rne(yv.y),
                                      f2bf_rne(yv.z), f2bf_rne(yv.w));
            *reinterpret_cast<ushort4*>(&Xs[row * 72 + k4]) = xs;
            *reinterpret_cast<ushort4*>(&Ys[row * 72 + k4]) = ys;
        }
    }
    __syncthreads();

    {
        const int rr = tid & 127;
        const unsigned short* src = (tid < 128) ? Xs : Ys;
        float s = 0.f;
        #pragma unroll
        for (int kk = 0; kk < 64; ++kk) {
            float v = bf2f(src[rr * 72 + kk]);
            s = fmaf(v, v, s);
        }
        if (tid < 128) xn2[rr] = s; else ym2[rr] = s;
    }
    __syncthreads();

    const int w    = __builtin_amdgcn_readfirstlane(tid >> 6);
    const int lane = tid & 63;
    const int wr = w >> 1, wc = w & 1;
    const int lo = lane & 15, hi = lane >> 4;

    f32x4 acc[4][4];
    #pragma unroll
    for (int ri = 0; ri < 4; ++ri)
        #pragma unroll
        for (int ci = 0; ci < 4; ++ci) acc[ri][ci] = f32x4{0.f, 0.f, 0.f, 0.f};

    #pragma unroll
    for (int ks = 0; ks < 2; ++ks) {
        short8v a[4], bf[4];
        const int kb = ks * 32 + hi * 8;
        #pragma unroll
        for (int ri = 0; ri < 4; ++ri)
            a[ri] = *reinterpret_cast<const short8v*>(
                        &Xs[(wr * 64 + ri * 16 + lo) * 72 + kb]);
        #pragma unroll
        for (int ci = 0; ci < 4; ++ci)
            bf[ci] = *reinterpret_cast<const short8v*>(
                        &Ys[(wc * 64 + ci * 16 + lo) * 72 + kb]);
        #pragma unroll
        for (int ri = 0; ri < 4; ++ri)
            #pragma unroll
            for (int ci = 0; ci < 4; ++ci)
                acc[ri][ci] = __builtin_amdgcn_mfma_f32_16x16x32_bf16(
                                  a[ri], bf[ci], acc[ri][ci], 0, 0, 0);
    }

    #pragma unroll
    for (int ri = 0; ri < 4; ++ri)
        #pragma unroll
        for (int ci = 0; ci < 4; ++ci)
            #pragma unroll
            for (int rg = 0; rg < 4; ++rg) {
                const int row = wr * 64 + ri * 16 + hi * 4 + rg;
                const int col = wc * 64 + ci * 16 + lo;
                float val = fmaf(-2.f, acc[ri][ci][rg], xn2[row] + ym2[col]) * LOG2E;
                Ct[row * 132 + col] = f2bf_rne(val);
            }
    __syncthreads();

    const int grp = tid >> 6;
    const int g00 = n0 + m0;
    for (int d = grp; d < 255; d += 4) {
        const int tn_lo = max(0, d - 127);
        const int tn_hi = min(127, d);
        const int dg    = g00 + d;
        const int base  = dOffm(dg) + n0;
        for (int o = lane; o <= tn_hi - tn_lo; o += 64) {
            const int tn = tn_lo + o;
            Db[base + tn] = Ct[tn * 132 + (d - tn)];
        }
    }
}

// ---------------- Kernel B: E-domain (linear) systolic recurrence ----------------
// State per lane (row r): (F, A) with v = A - log2(F); E = 2^-v = F*2^-A.
// Zero-state (E=0, i.e. BIG) := (F=1, A=ALARGE) — its shift clamps to -96 so it
// contributes 2^-96-scale noise, never dominates, and needs no predicates.
// Per step: A_ref = min3(A); terms aligned by exponent-bit adds (shift in
// [-96,0]); F_new = w*(F0+F1+F2), A_new = A_ref + rint(D); w = 2^(rint(D)-D)
// precomputed off-chain from prefetched D. Own-F renorm every 4 steps keeps
// exponents in clamp-safe range. Chain = DPP + bitadd + 2 fadd + fmul (~36cy),
// no transcendentals. Schedule/ring/preload/capture identical to round 14.
__global__ __launch_bounds__(512)
void softdtw_exp16(const unsigned short* __restrict__ Dch,
                   const int* __restrict__ lengths, float* __restrict__ out)
{
    __shared__ float ringF[8][64];
    __shared__ int   ringA[8][64];
    const int b    = blockIdx.x;
    const int t    = threadIdx.x;
    const int lane = t & 63;
    const int W    = __builtin_amdgcn_readfirstlane(t >> 6);   // scalar 0..7
    const int L    = lengths[b];
    const int r    = (W << 6) + lane;       // 0-based row
    const unsigned short* Dbat = Dch + (size_t)b * CELLS;

    if (t < 64) { ringF[0][t] = 1.0f; ringA[0][t] = ALARGE; }
    __syncthreads();

    const bool l0   = (lane == 0);
    const bool iok  = (r <= L - 1);
    const int  gcap = (r == L - 1) ? (L + 510) : -1;
    const int  qlL  = (L + 510) >> 4;
    const bool rowsOK = ((W << 6) + 64) <= L;
    const int  q0 = 4 * W;
    const int  ql = min(4 * W + 35, qlL);
    const int  cmax = qlL + 8;

    float Fo = 1.0f, Fn1 = 1.0f, Fn2 = 1.0f;
    int   Ao = ALARGE, An1 = ALARGE, An2 = ALARGE;
    if (W == 0 && l0) { Fn2 = 1.0f; An2 = 0; }     // DP origin seed: E=1
    float resF = 1.0f; int resA = 0;

    // prologue: raw u16 loads for window q0
    unsigned Dwin[16];
    {
        int sb = dOffm(q0 * 16);
        int gg = q0 * 16;
        #pragma unroll
        for (int s = 0; s < 16; ++s) {
            Dwin[s] = Dbat[sb + r];
            int d1 = (gg < 512) ? (gg + 1) : (1023 - gg);
            sb += d1 - ((gg >= 511) ? 1 : 0);
            ++gg;
        }
    }

    for (int c = 0; c < cmax; ++c) {
        const int q = c - W;
        if (q >= q0 && q <= ql) {
            const int g0 = q * 16;
            const int rbase = g0 & 63;

            // ring windows in (uniform broadcast b128 reads, off the chain)
            float4 rvF[4]; int4 rvA[4];
            {
                const float4* rpF = reinterpret_cast<const float4*>(&ringF[W][rbase]);
                const int4*   rpA = reinterpret_cast<const int4*>(&ringA[W][rbase]);
                #pragma unroll
                for (int u = 0; u < 4; ++u) { rvF[u] = rpF[u]; rvA[u] = rpA[u]; }
            }

            const bool doNext = (q + 1 <= ql);
            int gN  = doNext ? (g0 + 16) : 0;
            int sbN = dOffm(gN);

            float4 expvF[4]; int4 expvA[4];
            const bool fastC = rowsOK && q >= q0 + 4 && q <= q0 + 31 && q != qlL;

            auto body = [&](auto FASTC) {
                constexpr bool FAST = decltype(FASTC)::value;
                #pragma unroll
                for (int s = 0; s < 16; ++s) {
                    const int g = g0 + s;
                    // per-step D prep (off-chain)
                    const float Df  = bf2f((unsigned short)Dwin[s]);
                    const float rdf = rintf(Df);
                    const int   rdi = (int)rdf;
                    const float w   = __builtin_amdgcn_exp2f(rdf - Df);
                    // anchor + clamped shifts (int, off-chain)
                    const int Ar = min(Ao, min(An1, An2));
                    const int s0 = max(Ar - Ao,  -96);
                    const int s1 = max(Ar - An1, -96);
                    const int s2 = max(Ar - An2, -96);
                    // aligned terms + linear combine (the whole chain)
                    float F0 = expadd(Fo,  s0);
                    float F1 = expadd(Fn1, s1);
                    float F2 = expadd(Fn2, s2);
                    float Fn = w * ((F0 + F1) + F2);
                    int   An = Ar + rdi;
                    if (!FAST) {
                        const bool jok = (unsigned)(g - r) < (unsigned)Mc;
                        const bool valid = jok && iok;
                        Fn = valid ? Fn : 1.0f;
                        An = valid ? An : ALARGE;
                        if (g == gcap) { resF = Fn; resA = An; }
                    }
                    // own renorm every 4 steps (keeps exponent clamp-safe)
                    if ((s & 3) == 3) {
                        int e = ((__builtin_bit_cast(int, Fn) >> 23) & 0xFF) - 127;
                        Fn = __builtin_bit_cast(float,
                                 __builtin_bit_cast(int, Fn) - (e << 23));
                        An += e;
                    }
                    // refill slot s from window q+1
                    Dwin[s] = Dbat[sbN + r];
                    {
                        int d1 = (gN < 512) ? (gN + 1) : (1023 - gN);
                        sbN += d1 - ((gN >= 511) ? 1 : 0);
                        ++gN;
                    }
                    f4set(expvF[s >> 2], s, Fn);
                    i4set(expvA[s >> 2], s, An);
                    // neighbor propagation
                    const float shF = dpp_shr1_f(Fn, 1.0f);
                    const int   shA = dpp_shr1_i(An, ALARGE);
                    Fn2 = Fn1; An2 = An1;
                    Fn1 = l0 ? f4c(rvF[s >> 2], s) : shF;
                    An1 = l0 ? i4c(rvA[s >> 2], s) : shA;
                    Fo = Fn; Ao = An;
                }
            };
            if (fastC) body(TrueC{}); else body(FalseC{});

            // ring export (lane 63 only): F and A windows
            if (W < 7 && lane == 63) {
                float* reF = &ringF[W + 1][rbase];
                int*   reA = &ringA[W + 1][rbase];
                #pragma unroll
                for (int u = 0; u < 4; ++u) {
                    reinterpret_cast<float4*>(reF)[u] = expvF[u];
                    reinterpret_cast<int4*>(reA)[u]   = expvA[u];
                }
            }
        } else if (W > 0 && q == q0 - 1) {
            // preload: ring slots 62/63 = rows-above values at g=64W-2, 64W-1
            if (l0) {
                Fn1 = ringF[W][63]; An1 = ringA[W][63];
                Fn2 = ringF[W][62]; An2 = ringA[W][62];
            }
        }
        asm volatile("s_waitcnt lgkmcnt(0)" ::: "memory");  // ring writes visible
        __builtin_amdgcn_s_barrier();                       // no vmcnt drain
        asm volatile("" ::: "memory");
    }

    if (r == L - 1)
        out[b] = ((float)resA - __builtin_amdgcn_logf(resF)) * LN2;
}

// ---------------- Fallback (no workspace): fused on-the-fly D --------------------
__global__ __launch_bounds__(512)
void softdtw_fused(const float* __restrict__ X, const float* __restrict__ Y,
                   const int* __restrict__ lengths, float* __restrict__ out)
{
    const int b = blockIdx.x;
    const int t = threadIdx.x;
    const int i = t + 1;
    const int L = lengths[b];

    __shared__ float diag[3][Nc + 1];
    for (int c = t; c <= Nc; c += 512) {
        diag[0][c] = (c == 0) ? 0.f : BIGc;
        diag[1][c] = BIGc;
    }
    float xr[DIMc];
    const float* Xrow = X + ((size_t)b * Nc + t) * DIMc;
    #pragma unroll
    for (int d = 0; d < DIMc; d += 4) {
        float4 v = *reinterpret_cast<const float4*>(Xrow + d);
        xr[d] = v.x; xr[d+1] = v.y; xr[d+2] = v.z; xr[d+3] = v.w;
    }
    const float* Yb = Y + (size_t)b * Mc * DIMc;
    __syncthreads();

    float result = BIGc;
    int cur = 2, p1 = 1, p2 = 0;
    for (int k = 2; k <= Nc + Mc; ++k) {
        const int j = k - i;
        const bool valid = (j >= 1) && (j <= Mc) && (i <= L);
        float Dval = 0.f;
        if (valid) {
            const float* Yrow = Yb + (size_t)(j - 1) * DIMc;
            float s = 0.f;
            #pragma unroll
            for (int d = 0; d < DIMc; d += 4) {
                float4 v = *reinterpret_cast<const float4*>(Yrow + d);
                float d0 = xr[d] - v.x, d1 = xr[d+1] - v.y;
                float d2 = xr[d+2] - v.z, d3 = xr[d+3] - v.w;
                s = fmaf(d0,d0,s); s = fmaf(d1,d1,s); s = fmaf(d2,d2,s); s = fmaf(d3,d3,s);
            }
            Dval = s;
        }
        const float a2 = diag[p2][i-1], a1 = diag[p1][i-1], a0 = diag[p1][i];
        const float mn = fminf(a2, fminf(a1, a0));
        const float sm = mn - __logf(__expf(mn-a2) + __expf(mn-a1) + __expf(mn-a0));
        const float val = valid ? (Dval + sm) : BIGc;
        diag[cur][i] = val;
        if (t == 0) diag[cur][0] = BIGc;
        if (k == L + Mc && i == L) result = val;
        __syncthreads();
        const int tmp = p2; p2 = p1; p1 = cur; cur = tmp;
    }
    if (i == L) out[b] = result;
}

extern "C" void kernel_launch(void* const* d_in, const int* in_sizes, int n_in,
                              void* d_out, int out_size, void* d_ws, size_t ws_size,
                              hipStream_t stream) {
    const float* X = (const float*)d_in[0];
    const float* Y = (const float*)d_in[1];
    const int* lengths = (const int*)d_in[2];
    float* out = (float*)d_out;

    const size_t need = (size_t)Bc * CELLS * sizeof(unsigned short);  // 32 MiB
    if (ws_size >= need) {
        unsigned short* Dc = (unsigned short*)d_ws;
        compute_D_mfma<<<dim3(Bc, 16), 256, 0, stream>>>(X, Y, Dc);
        softdtw_exp16<<<Bc, 512, 0, stream>>>(Dc, lengths, out);
    } else {
        softdtw_fused<<<Bc, 512, 0, stream>>>(X, Y, lengths, out);
    }
}